// Round 2
// baseline (499.088 us; speedup 1.0000x reference)
//
#include <hip/hip_runtime.h>
#include <hip/hip_bf16.h>

// Problem constants (from reference setup_inputs)
#define M_TOK 8192
#define N_OUT 4096
#define K_IN  4096

#define SPARSIFY_BLOCKS 2048
#define CONVX_BLOCKS    6144
#define PREP_BLOCKS     (SPARSIFY_BLOCKS + CONVX_BLOCKS)

typedef __attribute__((ext_vector_type(8))) __bf16 bf16x8;
typedef __attribute__((ext_vector_type(4))) float f32x4;

__device__ __forceinline__ unsigned short f2bf(float f) {
    return __builtin_bit_cast(unsigned short, (__bf16)f);
}

// ---------------------------------------------------------------------------
// Kernel 1 (fused prep): blocks [0,2048) soft-threshold 2:4 sparsify of W
// (fp32 -> bf16 W_s + per-block partial dense/sparse sumsq); blocks
// [2048,8192) convert x fp32 -> bf16. Independent streams, one launch.
// ---------------------------------------------------------------------------
__global__ __launch_bounds__(256) void prep_kernel(
        const float* __restrict__ w,
        const float* __restrict__ x,
        unsigned short* __restrict__ wsb,
        unsigned short* __restrict__ xb,
        float* __restrict__ pd,     // [SPARSIFY_BLOCKS] partial dense_sq
        float* __restrict__ ps,     // [SPARSIFY_BLOCKS] partial sparse_sq
        int ngroups, int n4) {
    if (blockIdx.x < SPARSIFY_BLOCKS) {
        const int stride = SPARSIFY_BLOCKS * 256;
        float dsq = 0.0f, ssq = 0.0f;
        for (int gid = blockIdx.x * 256 + threadIdx.x; gid < ngroups;
             gid += stride) {
            const float4 g = ((const float4*)w)[gid];
            float a0 = fabsf(g.x), a1 = fabsf(g.y);
            float a2 = fabsf(g.z), a3 = fabsf(g.w);
            float lo1 = fminf(a0, a1), hi1 = fmaxf(a0, a1);
            float lo2 = fminf(a2, a3), hi2 = fmaxf(a2, a3);
            float t = fminf(fmaxf(lo1, lo2), fminf(hi1, hi2));
            float s0 = (a0 > t) ? copysignf(a0 - t, g.x) : 0.0f;
            float s1 = (a1 > t) ? copysignf(a1 - t, g.y) : 0.0f;
            float s2 = (a2 > t) ? copysignf(a2 - t, g.z) : 0.0f;
            float s3 = (a3 > t) ? copysignf(a3 - t, g.w) : 0.0f;
            dsq += g.x * g.x + g.y * g.y + g.z * g.z + g.w * g.w;
            ssq += s0 * s0 + s1 * s1 + s2 * s2 + s3 * s3;
            ushort4 o;
            o.x = f2bf(s0); o.y = f2bf(s1); o.z = f2bf(s2); o.w = f2bf(s3);
            ((ushort4*)wsb)[gid] = o;
        }
        for (int off = 32; off > 0; off >>= 1) {
            dsq += __shfl_down(dsq, off);
            ssq += __shfl_down(ssq, off);
        }
        __shared__ float sd[4], ss[4];
        int lane = threadIdx.x & 63, wv = threadIdx.x >> 6;
        if (lane == 0) { sd[wv] = dsq; ss[wv] = ssq; }
        __syncthreads();
        if (threadIdx.x == 0) {
            pd[blockIdx.x] = sd[0] + sd[1] + sd[2] + sd[3];
            ps[blockIdx.x] = ss[0] + ss[1] + ss[2] + ss[3];
        }
    } else {
        const int stride = CONVX_BLOCKS * 256;
        for (int i = (blockIdx.x - SPARSIFY_BLOCKS) * 256 + threadIdx.x;
             i < n4; i += stride) {
            float4 v = ((const float4*)x)[i];
            ushort4 o;
            o.x = f2bf(v.x); o.y = f2bf(v.y); o.z = f2bf(v.z); o.w = f2bf(v.w);
            ((ushort4*)xb)[i] = o;
        }
    }
}

// ---------------------------------------------------------------------------
// Kernel 2: 256x256-tile 8-phase GEMM (m201 quadrant schedule, plain HIP).
// C[M][N] = scale * (A[M][K] @ B[N][K]^T) + bias[N]
//
//  - BM=BN=256, BK=64, 8 waves (2M x 4N), per-wave output 128x64.
//  - LDS 128 KiB: 2 buffers x (A 32 KiB + B 32 KiB), [16][32]-subtiled with
//    st_16x32 swizzle (byte ^= ((byte>>9)&1)<<5). global_load_lds writes
//    linearly; swizzle applied on per-lane GLOBAL source address (involution)
//    and on ds_read byte address (rule #21: both-sides-or-neither).
//  - 4 phases per K-tile, one C-quadrant each (balanced ds_reads 12/4/8/0):
//      P0: read a[0-3],b0,b1            -> MFMA Q00 (m0-3 x n0-1)
//      P1: read b2,b3                   -> MFMA Q01 (m0-3 x n2-3)
//      P2: read a[4-7]; stage B(t+2)    -> MFMA Q11 (m4-7 x n2-3)
//      P3: stage A(t+2); MFMA Q10 (m4-7 x n0-1); vmcnt(8)
//    B reads finish at P1 (stage B at P2 safe); A reads finish at P2
//    (stage A at P3 safe). 8 loads/tile in flight; vmcnt(8) once per tile
//    retires tile t+1's loads, never drains to 0 in the main loop.
//  - Scale (norm-matching, clipped) computed per-block in the epilogue from
//    sparsify's partials (16 KB, L2-resident) — no separate scale kernel.
// ---------------------------------------------------------------------------
#define BM 256
#define BN 256
#define BK 64
#define NT (K_IN / BK)   // 64 K-tiles

#define GBAR() do { asm volatile("" ::: "memory"); \
                    __builtin_amdgcn_s_barrier();  \
                    asm volatile("" ::: "memory"); } while (0)

// HT: 0=A.h0 1=A.h1 2=B.h0 3=B.h1 (literal). Element offsets:
// buf stride 32768, B region +16384, half +8192, load1 +4096, wave +512.
#define STAGE(GP, O0, O1, HT, TAU)                                             \
  do {                                                                         \
    const int _t = (TAU);                                                      \
    unsigned short* _d = smem + ((_t & 1) << 15) + (((HT) >> 1) << 14) +       \
                         (((HT) & 1) << 13) + (wv << 9);                       \
    __builtin_amdgcn_global_load_lds(                                          \
        (const __attribute__((address_space(1))) void*)((GP) + (O0) + _t * 64),\
        (__attribute__((address_space(3))) void*)_d, 16, 0, 0);                \
    __builtin_amdgcn_global_load_lds(                                          \
        (const __attribute__((address_space(1))) void*)((GP) + (O1) + _t * 64),\
        (__attribute__((address_space(3))) void*)(_d + 4096), 16, 0, 0);       \
  } while (0)

// One C-quadrant: rows MIB..MIB+3 (from aL), cols NA,NB (frags BA,BB). 16 MFMA.
#define STRIPQ(MIB, NA, NB, BA, BB)                                            \
  do {                                                                         \
    __builtin_amdgcn_s_setprio(1);                                             \
    _Pragma("unroll")                                                          \
    for (int mi = 0; mi < 4; ++mi) {                                           \
      acc[(MIB) + mi][NA] = __builtin_amdgcn_mfma_f32_16x16x32_bf16(           \
          aL[mi][0], BA[0], acc[(MIB) + mi][NA], 0, 0, 0);                     \
      acc[(MIB) + mi][NB] = __builtin_amdgcn_mfma_f32_16x16x32_bf16(           \
          aL[mi][0], BB[0], acc[(MIB) + mi][NB], 0, 0, 0);                     \
    }                                                                          \
    _Pragma("unroll")                                                          \
    for (int mi = 0; mi < 4; ++mi) {                                           \
      acc[(MIB) + mi][NA] = __builtin_amdgcn_mfma_f32_16x16x32_bf16(           \
          aL[mi][1], BA[1], acc[(MIB) + mi][NA], 0, 0, 0);                     \
      acc[(MIB) + mi][NB] = __builtin_amdgcn_mfma_f32_16x16x32_bf16(           \
          aL[mi][1], BB[1], acc[(MIB) + mi][NB], 0, 0, 0);                     \
    }                                                                          \
    __builtin_amdgcn_s_setprio(0);                                             \
  } while (0)

__global__ __launch_bounds__(512, 2) void gemm_8phase_kernel(
        const unsigned short* __restrict__ A,   // xb  bf16 [M][K]
        const unsigned short* __restrict__ B,   // wsb bf16 [N][K]
        const float* __restrict__ bias,         // [N]
        const float* __restrict__ pd,           // [SPARSIFY_BLOCKS]
        const float* __restrict__ ps,           // [SPARSIFY_BLOCKS]
        float* __restrict__ C) {                // [M][N]
    __shared__ __align__(16) unsigned short smem[65536];  // 128 KiB

    const int tid  = threadIdx.x;          // 0..511
    const int lane = tid & 63;
    const int wv   = tid >> 6;             // 0..7
    const int wm   = wv >> 2;              // 0..1  (M half)
    const int wn   = wv & 3;               // 0..3  (N quarter)
    const int quad = lane >> 4;
    const int l16  = lane & 15;

    // XCD-aware bijective swizzle: 512 wgs, 512 % 8 == 0
    const int nwg = (M_TOK / BM) * (N_OUT / BN);          // 512
    const int swz = (blockIdx.x & 7) * (nwg >> 3) + (blockIdx.x >> 3);
    const int m0 = (swz >> 4) * BM;                       // 32 M-tiles
    const int n0 = (swz & 15) * BN;                       // 16 N-tiles

    // --- per-thread staging source map (inverse st_16x32 swizzle) ---------
    unsigned offA[2][2], offB[2][2];       // [half][load_i], element offsets
#pragma unroll
    for (int i = 0; i < 2; ++i) {
        const int idx = i * 512 + tid;                    // 0..1023
        const int s   = idx >> 6;                         // subtile 0..15
        const int bb  = (idx & 63) << 4;                  // byte in subtile
        const int bl  = bb ^ (((bb >> 9) & 1) << 5);      // logical byte
        const int row = (s >> 1) * 16 + (bl >> 6);        // 0..127
        const int col = (s & 1) * 32 + ((bl & 63) >> 1);  // 0,8,..,56
#pragma unroll
        for (int h = 0; h < 2; ++h) {
            offA[h][i] = (unsigned)(m0 + h * 128 + row) * K_IN + col;
            offB[h][i] = (unsigned)(n0 + h * 128 + row) * K_IN + col;
        }
    }

    // --- per-thread ds_read addressing (swizzled) -------------------------
    const unsigned innerE =
        (unsigned)(((l16 * 64 + quad * 16) ^ (((l16 >> 3) & 1) << 5)) >> 1);
    const unsigned aoff = (unsigned)(wm << 13) + innerE;
    const unsigned boff = 16384u + ((wn >> 1) << 13) + ((wn & 1) << 12) + innerE;

    f32x4 acc[8][4] = {};

    // --- prologue: stage tiles 0 and 1 (8 + 8 loads) ----------------------
    STAGE(A, offA[0][0], offA[0][1], 0, 0);
    STAGE(A, offA[1][0], offA[1][1], 1, 0);
    STAGE(B, offB[0][0], offB[0][1], 2, 0);
    STAGE(B, offB[1][0], offB[1][1], 3, 0);
    STAGE(A, offA[0][0], offA[0][1], 0, 1);
    STAGE(A, offA[1][0], offA[1][1], 1, 1);
    STAGE(B, offB[0][0], offB[0][1], 2, 1);
    STAGE(B, offB[1][0], offB[1][1], 3, 1);
    asm volatile("s_waitcnt vmcnt(8)" ::: "memory");  // tile 0 landed
    GBAR();

    for (int t = 0; t < NT; ++t) {
        const unsigned bufo = (unsigned)((t & 1) << 15);
        const unsigned ba = bufo + aoff;
        const unsigned bb = bufo + boff;
        bf16x8 aL[4][2], b0[2], b1[2], b2[2], b3[2];

        // ---- phase 0: read a[0-3] + b0,b1 (12 reads) -> Q00
#pragma unroll
        for (int mi = 0; mi < 4; ++mi) {
            aL[mi][0] = *(const bf16x8*)(smem + ba + (mi << 10));
            aL[mi][1] = *(const bf16x8*)(smem + ba + (mi << 10) + 512);
        }
        b0[0] = *(const bf16x8*)(smem + bb);
        b0[1] = *(const bf16x8*)(smem + bb + 512);
        b1[0] = *(const bf16x8*)(smem + bb + 1024);
        b1[1] = *(const bf16x8*)(smem + bb + 1536);
        GBAR();
        STRIPQ(0, 0, 1, b0, b1);
        GBAR();

        // ---- phase 1: read b2,b3 (4 reads) -> Q01
        b2[0] = *(const bf16x8*)(smem + bb + 2048);
        b2[1] = *(const bf16x8*)(smem + bb + 2560);
        b3[0] = *(const bf16x8*)(smem + bb + 3072);
        b3[1] = *(const bf16x8*)(smem + bb + 3584);
        GBAR();
        STRIPQ(0, 2, 3, b2, b3);
        GBAR();

        // ---- phase 2: read a[4-7] (8 reads); stage B(t+2) -> Q11
        //      (all B reads of tile t finished at P1 R2 barrier)
#pragma unroll
        for (int mi = 0; mi < 4; ++mi) {
            aL[mi][0] = *(const bf16x8*)(smem + ba + ((4 + mi) << 10));
            aL[mi][1] = *(const bf16x8*)(smem + ba + ((4 + mi) << 10) + 512);
        }
        if (t < NT - 2) {
            STAGE(B, offB[0][0], offB[0][1], 2, t + 2);
            STAGE(B, offB[1][0], offB[1][1], 3, t + 2);
        }
        GBAR();
        STRIPQ(4, 2, 3, b2, b3);
        GBAR();

        // ---- phase 3: stage A(t+2) -> Q10; vmcnt(8)
        //      (all A reads of tile t finished at P2 R2 barrier)
        if (t < NT - 2) {
            STAGE(A, offA[0][0], offA[0][1], 0, t + 2);
            STAGE(A, offA[1][0], offA[1][1], 1, t + 2);
        }
        GBAR();
        STRIPQ(4, 0, 1, b0, b1);
        if (t < NT - 2) asm volatile("s_waitcnt vmcnt(8)" ::: "memory");
        else            asm volatile("s_waitcnt vmcnt(0)" ::: "memory");
        GBAR();
    }

    // --- epilogue: per-block scale reduce (partials are L2-resident) ------
    float d = 0.0f, s = 0.0f;
#pragma unroll
    for (int k = 0; k < SPARSIFY_BLOCKS / 512; ++k) {
        d += pd[tid + k * 512];
        s += ps[tid + k * 512];
    }
    for (int off = 32; off > 0; off >>= 1) {
        d += __shfl_down(d, off);
        s += __shfl_down(s, off);
    }
    float* fs = (float*)smem;   // main loop done (post final GBAR), LDS free
    if (lane == 0) { fs[wv] = d; fs[8 + wv] = s; }
    __syncthreads();
    float dt = 0.0f, st = 0.0f;
#pragma unroll
    for (int k = 0; k < 8; ++k) { dt += fs[k]; st += fs[8 + k]; }
    st = fmaxf(st, 1e-12f);
    const float scale = fminf(fmaxf(sqrtf(dt / st), 0.1f), 10.0f);

    // --- scale + bias, fp32 store -----------------------------------------
#pragma unroll
    for (int p = 0; p < 4; ++p) {
        const int col = n0 + wn * 64 + p * 16 + l16;
        const float bv = bias[col];
#pragma unroll
        for (int mi = 0; mi < 8; ++mi) {
#pragma unroll
            for (int r = 0; r < 4; ++r) {
                const int row = m0 + wm * 128 + mi * 16 + quad * 4 + r;
                C[(size_t)row * N_OUT + col] = scale * acc[mi][p][r] + bv;
            }
        }
    }
}

// ---------------------------------------------------------------------------
// Launch: 2 kernels total (prep fused, scale folded into GEMM epilogue)
// ---------------------------------------------------------------------------
extern "C" void kernel_launch(void* const* d_in, const int* in_sizes, int n_in,
                              void* d_out, int out_size, void* d_ws, size_t ws_size,
                              hipStream_t stream) {
    const float* x      = (const float*)d_in[0];   // [8192][4096]
    const float* weight = (const float*)d_in[1];   // [4096][4096]
    const float* bias   = (const float*)d_in[2];   // [4096]
    float* out          = (float*)d_out;           // [8192][4096]

    char* ws = (char*)d_ws;
    float* pd           = (float*)(ws + 1024);                // 2048 floats
    float* psm          = (float*)(ws + 1024 + 4 * SPARSIFY_BLOCKS);
    unsigned short* wsb = (unsigned short*)(ws + 32768);      // 32 MB bf16 W_s
    unsigned short* xb  = (unsigned short*)(ws + 32768 + (size_t)N_OUT * K_IN * 2); // 64 MB bf16 x

    // 1) fused: sparsify W (+ partial sumsqs) || convert x -> bf16
    const int ngroups = N_OUT * K_IN / 4;   // 4,194,304
    const int n4 = M_TOK * K_IN / 4;        // 8,388,608
    prep_kernel<<<PREP_BLOCKS, 256, 0, stream>>>(weight, x, wsb, xb, pd, psm,
                                                 ngroups, n4);

    // 2) 256^2 8-phase GEMM + scale/bias epilogue
    const int nwg = (M_TOK / BM) * (N_OUT / BN);   // 512
    gemm_8phase_kernel<<<dim3(nwg), dim3(512), 0, stream>>>(xb, wsb, bias,
                                                            pd, psm, out);
}

// Round 3
// 472.639 us; speedup vs baseline: 1.0560x; 1.0560x over previous
//
#include <hip/hip_runtime.h>
#include <hip/hip_bf16.h>

// Problem constants (from reference setup_inputs)
#define M_TOK 8192
#define N_OUT 4096
#define K_IN  4096

#define SPARSIFY_BLOCKS 2048
#define CONVX_BLOCKS    6144
#define PREP_BLOCKS     (SPARSIFY_BLOCKS + CONVX_BLOCKS)

typedef __attribute__((ext_vector_type(8))) __bf16 bf16x8;
typedef __attribute__((ext_vector_type(4))) float f32x4;

__device__ __forceinline__ unsigned short f2bf(float f) {
    return __builtin_bit_cast(unsigned short, (__bf16)f);
}

// ---------------------------------------------------------------------------
// Kernel 1 (fused prep): blocks [0,2048) soft-threshold 2:4 sparsify of W
// (fp32 -> bf16 W_s + per-block partial dense/sparse sumsq); blocks
// [2048,8192) convert x fp32 -> bf16. Independent streams, one launch.
// ---------------------------------------------------------------------------
__global__ __launch_bounds__(256) void prep_kernel(
        const float* __restrict__ w,
        const float* __restrict__ x,
        unsigned short* __restrict__ wsb,
        unsigned short* __restrict__ xb,
        float* __restrict__ pd,     // [SPARSIFY_BLOCKS] partial dense_sq
        float* __restrict__ ps,     // [SPARSIFY_BLOCKS] partial sparse_sq
        int ngroups, int n4) {
    if (blockIdx.x < SPARSIFY_BLOCKS) {
        const int stride = SPARSIFY_BLOCKS * 256;
        float dsq = 0.0f, ssq = 0.0f;
        for (int gid = blockIdx.x * 256 + threadIdx.x; gid < ngroups;
             gid += stride) {
            const float4 g = ((const float4*)w)[gid];
            float a0 = fabsf(g.x), a1 = fabsf(g.y);
            float a2 = fabsf(g.z), a3 = fabsf(g.w);
            float lo1 = fminf(a0, a1), hi1 = fmaxf(a0, a1);
            float lo2 = fminf(a2, a3), hi2 = fmaxf(a2, a3);
            float t = fminf(fmaxf(lo1, lo2), fminf(hi1, hi2));
            float s0 = (a0 > t) ? copysignf(a0 - t, g.x) : 0.0f;
            float s1 = (a1 > t) ? copysignf(a1 - t, g.y) : 0.0f;
            float s2 = (a2 > t) ? copysignf(a2 - t, g.z) : 0.0f;
            float s3 = (a3 > t) ? copysignf(a3 - t, g.w) : 0.0f;
            dsq += g.x * g.x + g.y * g.y + g.z * g.z + g.w * g.w;
            ssq += s0 * s0 + s1 * s1 + s2 * s2 + s3 * s3;
            ushort4 o;
            o.x = f2bf(s0); o.y = f2bf(s1); o.z = f2bf(s2); o.w = f2bf(s3);
            ((ushort4*)wsb)[gid] = o;
        }
        for (int off = 32; off > 0; off >>= 1) {
            dsq += __shfl_down(dsq, off);
            ssq += __shfl_down(ssq, off);
        }
        __shared__ float sd[4], ss[4];
        int lane = threadIdx.x & 63, wv = threadIdx.x >> 6;
        if (lane == 0) { sd[wv] = dsq; ss[wv] = ssq; }
        __syncthreads();
        if (threadIdx.x == 0) {
            pd[blockIdx.x] = sd[0] + sd[1] + sd[2] + sd[3];
            ps[blockIdx.x] = ss[0] + ss[1] + ss[2] + ss[3];
        }
    } else {
        const int stride = CONVX_BLOCKS * 256;
        for (int i = (blockIdx.x - SPARSIFY_BLOCKS) * 256 + threadIdx.x;
             i < n4; i += stride) {
            float4 v = ((const float4*)x)[i];
            ushort4 o;
            o.x = f2bf(v.x); o.y = f2bf(v.y); o.z = f2bf(v.z); o.w = f2bf(v.w);
            ((ushort4*)xb)[i] = o;
        }
    }
}

// ---------------------------------------------------------------------------
// Kernel 2: 256x256-tile 8-phase GEMM — faithful m201 schedule.
// C[M][N] = scale * (A[M][K] @ B[N][K]^T) + bias[N]
//
//  - BM=BN=256, BK=64, 8 waves (2M x 4N), per-wave output 128x64.
//  - LDS 128 KiB: 2 buffers x (A 32 KiB + B 32 KiB), [16][32]-subtiled with
//    st_16x32 swizzle (byte ^= ((byte>>9)&1)<<5). global_load_lds writes
//    linearly; swizzle applied on per-lane GLOBAL source (involution) and on
//    ds_read byte address (rule #21).
//  - 4 phases per K-tile, one C-quadrant each; ds_reads 12/4/8/0; EXACTLY
//    2 global_load_lds issued per phase (the m196/m201 interleave lever):
//      P0: read a[0-3],b0,b1 (12; lgkmcnt(8) hint); stage A.l0s(t+1) -> Q00
//      P1: read b2,b3 (4);   stage A.l1s(t+1); vmcnt(8)            -> Q01
//      P2: read a[4-7] (8);  stage B.h0(t+2)                       -> Q11
//      P3:                   stage B.h1(t+2); vmcnt(6)             -> Q10
//    A half-tile load0 = rows 0-63 (used at P0), load1 = rows 64-127 (P2):
//    the split-stage keeps first-use aligned with retirement order.
//    A stages (P0/P1) target the OTHER buffer (last read tile t-1 P2, >=2
//    barriers past); B stages (P2/P3) target the current buffer (B reads done
//    at P1's closing barrier). vmcnt(8)@P1 retires A.l1s needed by P2 (4
//    phases slack); vmcnt(6)@P3 retires next tile's A.l0s + B halves (3.5-6
//    phases slack). Never drains to 0 mid-loop; tail: 2 -> 0.
//  - Scale (norm-matching, clipped) computed per-block in the epilogue from
//    sparsify's partials (16 KB, L2-resident) — no separate scale kernel.
// ---------------------------------------------------------------------------
#define BM 256
#define BN 256
#define BK 64
#define NT (K_IN / BK)   // 64 K-tiles

#define GBAR() do { asm volatile("" ::: "memory"); \
                    __builtin_amdgcn_s_barrier();  \
                    asm volatile("" ::: "memory"); } while (0)

// One 16-B-per-lane global_load_lds of half-tile quarter LI (0: rows 0-63,
// 1: rows 64-127). HT: 0=A.h0 1=A.h1 2=B.h0 3=B.h1 (literal). Element
// offsets: buf stride 32768, B region +16384, half +8192, LI +4096, wave +512.
#define STAGE1(GP, OFF, HT, TAU, LI)                                           \
  do {                                                                         \
    const int _t = (TAU);                                                      \
    unsigned short* _d = smem + ((_t & 1) << 15) + (((HT) >> 1) << 14) +       \
                         (((HT) & 1) << 13) + ((LI) << 12) + (wv << 9);        \
    __builtin_amdgcn_global_load_lds(                                          \
        (const __attribute__((address_space(1))) void*)((GP) + (OFF) + _t * 64),\
        (__attribute__((address_space(3))) void*)_d, 16, 0, 0);                \
  } while (0)

// One C-quadrant: rows MIB..MIB+3 (from aL), cols NA,NB (frags BA,BB). 16 MFMA.
#define STRIPQ(MIB, NA, NB, BA, BB)                                            \
  do {                                                                         \
    __builtin_amdgcn_s_setprio(1);                                             \
    _Pragma("unroll")                                                          \
    for (int mi = 0; mi < 4; ++mi) {                                           \
      acc[(MIB) + mi][NA] = __builtin_amdgcn_mfma_f32_16x16x32_bf16(           \
          aL[mi][0], BA[0], acc[(MIB) + mi][NA], 0, 0, 0);                     \
      acc[(MIB) + mi][NB] = __builtin_amdgcn_mfma_f32_16x16x32_bf16(           \
          aL[mi][0], BB[0], acc[(MIB) + mi][NB], 0, 0, 0);                     \
    }                                                                          \
    _Pragma("unroll")                                                          \
    for (int mi = 0; mi < 4; ++mi) {                                           \
      acc[(MIB) + mi][NA] = __builtin_amdgcn_mfma_f32_16x16x32_bf16(           \
          aL[mi][1], BA[1], acc[(MIB) + mi][NA], 0, 0, 0);                     \
      acc[(MIB) + mi][NB] = __builtin_amdgcn_mfma_f32_16x16x32_bf16(           \
          aL[mi][1], BB[1], acc[(MIB) + mi][NB], 0, 0, 0);                     \
    }                                                                          \
    __builtin_amdgcn_s_setprio(0);                                             \
  } while (0)

__global__ __launch_bounds__(512, 2) void gemm_8phase_kernel(
        const unsigned short* __restrict__ A,   // xb  bf16 [M][K]
        const unsigned short* __restrict__ B,   // wsb bf16 [N][K]
        const float* __restrict__ bias,         // [N]
        const float* __restrict__ pd,           // [SPARSIFY_BLOCKS]
        const float* __restrict__ ps,           // [SPARSIFY_BLOCKS]
        float* __restrict__ C) {                // [M][N]
    __shared__ __align__(16) unsigned short smem[65536];  // 128 KiB

    const int tid  = threadIdx.x;          // 0..511
    const int lane = tid & 63;
    const int wv   = tid >> 6;             // 0..7
    const int wm   = wv >> 2;              // 0..1  (M half)
    const int wn   = wv & 3;               // 0..3  (N quarter)
    const int quad = lane >> 4;
    const int l16  = lane & 15;

    // XCD-aware bijective swizzle: 512 wgs, 512 % 8 == 0
    const int nwg = (M_TOK / BM) * (N_OUT / BN);          // 512
    const int swz = (blockIdx.x & 7) * (nwg >> 3) + (blockIdx.x >> 3);
    const int m0 = (swz >> 4) * BM;                       // 32 M-tiles
    const int n0 = (swz & 15) * BN;                       // 16 N-tiles

    // --- per-thread staging source map (inverse st_16x32 swizzle) ---------
    unsigned offA[2][2], offB[2][2];       // [half][load_i], element offsets
#pragma unroll
    for (int i = 0; i < 2; ++i) {
        const int idx = i * 512 + tid;                    // 0..1023
        const int s   = idx >> 6;                         // subtile 0..15
        const int bb  = (idx & 63) << 4;                  // byte in subtile
        const int bl  = bb ^ (((bb >> 9) & 1) << 5);      // logical byte
        const int row = (s >> 1) * 16 + (bl >> 6);        // 0..127
        const int col = (s & 1) * 32 + ((bl & 63) >> 1);  // 0,8,..,56
#pragma unroll
        for (int h = 0; h < 2; ++h) {
            offA[h][i] = (unsigned)(m0 + h * 128 + row) * K_IN + col;
            offB[h][i] = (unsigned)(n0 + h * 128 + row) * K_IN + col;
        }
    }

    // --- per-thread ds_read addressing (swizzled) -------------------------
    const unsigned innerE =
        (unsigned)(((l16 * 64 + quad * 16) ^ (((l16 >> 3) & 1) << 5)) >> 1);
    const unsigned aoff = (unsigned)(wm << 13) + innerE;
    const unsigned boff = 16384u + ((wn >> 1) << 13) + ((wn & 1) << 12) + innerE;

    f32x4 acc[8][4] = {};

    // --- prologue ---------------------------------------------------------
    // Issue order establishes the steady-state invariant at tile-0 entry:
    //   landed(6): A.l0s(0), B0(0), B1(0)   (everything P0/P1 of tile 0 reads)
    //   in-flight(6): A.l1s(0), B0(1), B1(1)
    STAGE1(A, offA[0][0], 0, 0, 0);  STAGE1(A, offA[1][0], 1, 0, 0);
    STAGE1(B, offB[0][0], 2, 0, 0);  STAGE1(B, offB[0][1], 2, 0, 1);
    STAGE1(B, offB[1][0], 3, 0, 0);  STAGE1(B, offB[1][1], 3, 0, 1);
    STAGE1(A, offA[0][1], 0, 0, 1);  STAGE1(A, offA[1][1], 1, 0, 1);
    STAGE1(B, offB[0][0], 2, 1, 0);  STAGE1(B, offB[0][1], 2, 1, 1);
    STAGE1(B, offB[1][0], 3, 1, 0);  STAGE1(B, offB[1][1], 3, 1, 1);
    asm volatile("s_waitcnt vmcnt(6)" ::: "memory");
    GBAR();

    for (int t = 0; t < NT; ++t) {
        const unsigned bufo = (unsigned)((t & 1) << 15);
        const unsigned ba = bufo + aoff;
        const unsigned bb = bufo + boff;
        bf16x8 aL[4][2], b0[2], b1[2], b2[2], b3[2];

        // ---- P0: read a[0-3] + b0,b1 (12); stage A.l0s(t+1); Q00 ---------
#pragma unroll
        for (int mi = 0; mi < 4; ++mi) {
            aL[mi][0] = *(const bf16x8*)(smem + ba + (mi << 10));
            aL[mi][1] = *(const bf16x8*)(smem + ba + (mi << 10) + 512);
        }
        b0[0] = *(const bf16x8*)(smem + bb);
        b0[1] = *(const bf16x8*)(smem + bb + 512);
        b1[0] = *(const bf16x8*)(smem + bb + 1024);
        b1[1] = *(const bf16x8*)(smem + bb + 1536);
        if (t + 1 < NT) {
            STAGE1(A, offA[0][0], 0, t + 1, 0);
            STAGE1(A, offA[1][0], 1, t + 1, 0);
        }
        asm volatile("s_waitcnt lgkmcnt(8)" ::: "memory");
        GBAR();
        STRIPQ(0, 0, 1, b0, b1);
        GBAR();

        // ---- P1: read b2,b3 (4); stage A.l1s(t+1); vmcnt(8); Q01 ---------
        b2[0] = *(const bf16x8*)(smem + bb + 2048);
        b2[1] = *(const bf16x8*)(smem + bb + 2560);
        b3[0] = *(const bf16x8*)(smem + bb + 3072);
        b3[1] = *(const bf16x8*)(smem + bb + 3584);
        if (t + 1 < NT) {
            STAGE1(A, offA[0][1], 0, t + 1, 1);
            STAGE1(A, offA[1][1], 1, t + 1, 1);
        }
        GBAR();
        STRIPQ(0, 2, 3, b2, b3);
        if (t == NT - 1) asm volatile("s_waitcnt vmcnt(0)" ::: "memory");
        else             asm volatile("s_waitcnt vmcnt(8)" ::: "memory");
        GBAR();

        // ---- P2: read a[4-7] (8); stage B.h0(t+2); Q11 -------------------
#pragma unroll
        for (int mi = 0; mi < 4; ++mi) {
            aL[mi][0] = *(const bf16x8*)(smem + ba + ((4 + mi) << 10));
            aL[mi][1] = *(const bf16x8*)(smem + ba + ((4 + mi) << 10) + 512);
        }
        if (t + 2 < NT) {
            STAGE1(B, offB[0][0], 2, t + 2, 0);
            STAGE1(B, offB[0][1], 2, t + 2, 1);
        }
        GBAR();
        STRIPQ(4, 2, 3, b2, b3);
        GBAR();

        // ---- P3: stage B.h1(t+2); Q10; vmcnt(6|2|0) ----------------------
        if (t + 2 < NT) {
            STAGE1(B, offB[1][0], 3, t + 2, 0);
            STAGE1(B, offB[1][1], 3, t + 2, 1);
        }
        GBAR();
        STRIPQ(4, 0, 1, b0, b1);
        if (t < NT - 2)       asm volatile("s_waitcnt vmcnt(6)" ::: "memory");
        else if (t == NT - 2) asm volatile("s_waitcnt vmcnt(2)" ::: "memory");
        else                  asm volatile("s_waitcnt vmcnt(0)" ::: "memory");
        GBAR();
    }

    // --- epilogue: per-block scale reduce (partials are L2-resident) ------
    float d = 0.0f, s = 0.0f;
#pragma unroll
    for (int k = 0; k < SPARSIFY_BLOCKS / 512; ++k) {
        d += pd[tid + k * 512];
        s += ps[tid + k * 512];
    }
    for (int off = 32; off > 0; off >>= 1) {
        d += __shfl_down(d, off);
        s += __shfl_down(s, off);
    }
    float* fs = (float*)smem;   // main loop done (post final GBAR), LDS free
    if (lane == 0) { fs[wv] = d; fs[8 + wv] = s; }
    __syncthreads();
    float dt = 0.0f, st = 0.0f;
#pragma unroll
    for (int k = 0; k < 8; ++k) { dt += fs[k]; st += fs[8 + k]; }
    st = fmaxf(st, 1e-12f);
    const float scale = fminf(fmaxf(sqrtf(dt / st), 0.1f), 10.0f);

    // --- scale + bias, fp32 store -----------------------------------------
#pragma unroll
    for (int p = 0; p < 4; ++p) {
        const int col = n0 + wn * 64 + p * 16 + l16;
        const float bv = bias[col];
#pragma unroll
        for (int mi = 0; mi < 8; ++mi) {
#pragma unroll
            for (int r = 0; r < 4; ++r) {
                const int row = m0 + wm * 128 + mi * 16 + quad * 4 + r;
                C[(size_t)row * N_OUT + col] = scale * acc[mi][p][r] + bv;
            }
        }
    }
}

// ---------------------------------------------------------------------------
// Launch: 2 kernels total (prep fused, scale folded into GEMM epilogue)
// ---------------------------------------------------------------------------
extern "C" void kernel_launch(void* const* d_in, const int* in_sizes, int n_in,
                              void* d_out, int out_size, void* d_ws, size_t ws_size,
                              hipStream_t stream) {
    const float* x      = (const float*)d_in[0];   // [8192][4096]
    const float* weight = (const float*)d_in[1];   // [4096][4096]
    const float* bias   = (const float*)d_in[2];   // [4096]
    float* out          = (float*)d_out;           // [8192][4096]

    char* ws = (char*)d_ws;
    float* pd           = (float*)(ws + 1024);                // 2048 floats
    float* psm          = (float*)(ws + 1024 + 4 * SPARSIFY_BLOCKS);
    unsigned short* wsb = (unsigned short*)(ws + 32768);      // 32 MB bf16 W_s
    unsigned short* xb  = (unsigned short*)(ws + 32768 + (size_t)N_OUT * K_IN * 2); // 64 MB bf16 x

    // 1) fused: sparsify W (+ partial sumsqs) || convert x -> bf16
    const int ngroups = N_OUT * K_IN / 4;   // 4,194,304
    const int n4 = M_TOK * K_IN / 4;        // 8,388,608
    prep_kernel<<<PREP_BLOCKS, 256, 0, stream>>>(weight, x, wsb, xb, pd, psm,
                                                 ngroups, n4);

    // 2) 256^2 8-phase GEMM + scale/bias epilogue
    const int nwg = (M_TOK / BM) * (N_OUT / BN);   // 512
    gemm_8phase_kernel<<<dim3(nwg), dim3(512), 0, stream>>>(xb, wsb, bias,
                                                            pd, psm, out);
}